// Round 4
// baseline (565.395 us; speedup 1.0000x reference)
//
#include <hip/hip_runtime.h>

typedef unsigned short u16;
using f32x4  = __attribute__((ext_vector_type(4))) float;
using f32x16 = __attribute__((ext_vector_type(16))) float;
using s16x8  = __attribute__((ext_vector_type(8))) short;

// ---- helpers ---------------------------------------------------------------
static __device__ __forceinline__ u16 f2b(float f) {
  unsigned int u = __builtin_bit_cast(unsigned int, f);
  u = (u + 0x7fffu + ((u >> 16) & 1u)) >> 16;   // RNE, finite inputs only
  return (u16)u;
}
static __device__ __forceinline__ float b2f(u16 h) {
  unsigned int u = ((unsigned int)h) << 16;
  return __builtin_bit_cast(float, u);
}
static __device__ __forceinline__ unsigned int cvtpk(float lo, float hi) {
  unsigned int r;
  asm("v_cvt_pk_bf16_f32 %0, %1, %2" : "=v"(r) : "v"(lo), "v"(hi));
  return r;
}
static __device__ __forceinline__ void gload16(const void* g, void* l) {
  __builtin_amdgcn_global_load_lds(
      (const __attribute__((address_space(1))) void*)g,
      (__attribute__((address_space(3))) void*)l, 16, 0, 0);
}

// ---- fp32 -> bf16 elementwise (8/thread) -----------------------------------
__global__ __launch_bounds__(256) void conv_bf16(
    const float* __restrict__ in, u16* __restrict__ out, int n8)
{
  int i = blockIdx.x * 256 + threadIdx.x;
  if (i >= n8) return;
  float4 a = *(const float4*)(in + (size_t)i * 8);
  float4 b = *(const float4*)(in + (size_t)i * 8 + 4);
  __align__(16) u16 tmp[8] = {f2b(a.x), f2b(a.y), f2b(a.z), f2b(a.w),
                              f2b(b.x), f2b(b.y), f2b(b.z), f2b(b.w)};
  *(uint4*)(out + (size_t)i * 8) = *(const uint4*)tmp;
}

// ---- W[K][N] fp32 -> Wt[Npad][K] bf16 (transpose+convert, zero pad) --------
__global__ __launch_bounds__(256) void transpose_conv(
    const float* __restrict__ W, u16* __restrict__ Wt, int K, int N)
{
  __shared__ u16 tile[64][72];
  const int t = threadIdx.x;
  const int n0 = blockIdx.x * 64, k0 = blockIdx.y * 64;
  #pragma unroll
  for (int i = 0; i < 4; ++i) {
    int idx = i * 256 + t;
    int r = idx >> 4;
    int c = (idx & 15) << 2;
    float4 v = make_float4(0.f, 0.f, 0.f, 0.f);
    if (n0 + c < N) v = *(const float4*)(W + (size_t)(k0 + r) * N + n0 + c);
    tile[r][c + 0] = f2b(v.x);
    tile[r][c + 1] = f2b(v.y);
    tile[r][c + 2] = f2b(v.z);
    tile[r][c + 3] = f2b(v.w);
  }
  __syncthreads();
  #pragma unroll
  for (int i = 0; i < 2; ++i) {
    int idx = i * 256 + t;
    int rn = idx >> 3;
    int c8 = (idx & 7) << 3;
    __align__(16) u16 tmp[8];
    #pragma unroll
    for (int j = 0; j < 8; ++j) tmp[j] = tile[c8 + j][rn];
    *(uint4*)(Wt + (size_t)(n0 + rn) * K + k0 + c8) = *(const uint4*)tmp;
  }
}

// ---- GEMM 256x256, BK=64, 8 waves, deep-pipelined (counted vmcnt) ----------
// C[M,N] = A[M,K] * B^T; A bf16 [M][K], B bf16 [Npad][K], Npad%256==0, M%256==0,
// K%64==0. Grid = 1-D, gridDim.x % 8 == 0 (XCD-chunked swizzle).
// LDS: [2 dbuf][2 khalf][256 rows][32 k] per operand = 128 KiB.
// Schedule per K-tile t (4 phases): stage Hk1(t+1)@ph0, Hk0(t+2)@ph2;
// waits vmcnt(8) at end of ph1/ph3 (6-phase issue-to-use lead; never drains).
template<bool OUT_BF16>
__global__ __launch_bounds__(512, 2) void gemm256(
    const u16* __restrict__ A, const u16* __restrict__ B,
    void* __restrict__ Cptr, int M, int N, int K, int NB)
{
  __shared__ __align__(16) u16 sA[2][2][256 * 32];
  __shared__ __align__(16) u16 sB[2][2][256 * 32];

  const int t = threadIdx.x, lane = t & 63, w = t >> 6;
  const int lr = lane & 15, lg = lane >> 4;
  const int wr = w >> 2, wc = w & 3;        // 2 (M) x 4 (N) waves

  int bid = blockIdx.x;
  int q = gridDim.x >> 3;
  int swz = (bid & 7) * q + (bid >> 3);     // bijective: gridDim.x % 8 == 0
  const int m0 = (swz / NB) * 256, n0 = (swz % NB) * 256;

  // staging geometry: wave w, issue i covers rows (w*2+i)*16 + lane/4
  const int srow = w * 32 + (lane >> 2);
  const int skc  = (lane & 3) << 3;
  const u16* Ast = A + (size_t)(m0 + srow) * K + skc;
  const u16* Bst = B + (size_t)(n0 + srow) * K + skc;
  const int ldsoff = w * 2048;              // bytes within a 16 KiB half

  f32x4 acc[8][4] = {};
  const int nk = K >> 6;

#define STAGEU(tt, ks) do {                                                   \
    int bp_ = (tt) & 1; size_t kc_ = (size_t)(tt) * 64 + (size_t)(ks) * 32;   \
    gload16(Ast + kc_,                 (char*)&sA[bp_][ks][0] + ldsoff);      \
    gload16(Ast + kc_ + 16 * (size_t)K,(char*)&sA[bp_][ks][0] + ldsoff+1024); \
    gload16(Bst + kc_,                 (char*)&sB[bp_][ks][0] + ldsoff);      \
    gload16(Bst + kc_ + 16 * (size_t)K,(char*)&sB[bp_][ks][0] + ldsoff+1024); \
  } while (0)

#define LOADA(rh, ks, cur) do {                                               \
    const u16* ap_ = &sA[cur][ks][0] + ((wr*128 + (rh)*64 + lr) * 32) + lg*8; \
    af[0] = *(const s16x8*)(ap_);                                             \
    af[1] = *(const s16x8*)(ap_ + 16*32);                                     \
    af[2] = *(const s16x8*)(ap_ + 32*32);                                     \
    af[3] = *(const s16x8*)(ap_ + 48*32);                                     \
  } while (0)

#define LOADB(ks, cur) do {                                                   \
    const u16* bp2_ = &sB[cur][ks][0] + ((wc*64 + lr) * 32) + lg*8;           \
    bf[0] = *(const s16x8*)(bp2_);                                            \
    bf[1] = *(const s16x8*)(bp2_ + 16*32);                                    \
    bf[2] = *(const s16x8*)(bp2_ + 32*32);                                    \
    bf[3] = *(const s16x8*)(bp2_ + 48*32);                                    \
  } while (0)

#define MFMAQ(rh) do {                                                        \
    __builtin_amdgcn_s_setprio(1);                                            \
    _Pragma("unroll")                                                         \
    for (int m_ = 0; m_ < 4; ++m_)                                            \
      _Pragma("unroll")                                                       \
      for (int n_ = 0; n_ < 4; ++n_)                                          \
        acc[(rh)*4 + m_][n_] = __builtin_amdgcn_mfma_f32_16x16x32_bf16(       \
            af[m_], bf[n_], acc[(rh)*4 + m_][n_], 0, 0, 0);                   \
    __builtin_amdgcn_s_setprio(0);                                            \
  } while (0)

  // prologue: Hk0(0), Hk1(0), Hk0(1) in flight; ensure Hk0(0) landed
  STAGEU(0, 0);
  STAGEU(0, 1);
  if (nk > 1) STAGEU(1, 0);
  asm volatile("s_waitcnt vmcnt(8)" ::: "memory");
  __builtin_amdgcn_s_barrier();

  for (int kt = 0; kt < nk; ++kt) {
    const int cur = kt & 1;
    s16x8 af[4], bf[4];
    // ---- ph0: quadrant (rh0, k0); stage Hk1(kt+1) ----
    if (kt + 1 < nk) STAGEU(kt + 1, 1);
    LOADA(0, 0, cur); LOADB(0, cur);
    __builtin_amdgcn_s_barrier();
    MFMAQ(0);
    __builtin_amdgcn_s_barrier();
    // ---- ph1: quadrant (rh1, k0) ----
    LOADA(1, 0, cur);
    __builtin_amdgcn_s_barrier();
    MFMAQ(1);
    if (kt + 1 < nk) asm volatile("s_waitcnt vmcnt(8)" ::: "memory");
    else             asm volatile("s_waitcnt vmcnt(0)" ::: "memory");
    __builtin_amdgcn_s_barrier();
    // ---- ph2: quadrant (rh0, k1); stage Hk0(kt+2) ----
    if (kt + 2 < nk) STAGEU(kt + 2, 0);
    LOADA(0, 1, cur); LOADB(1, cur);
    __builtin_amdgcn_s_barrier();
    MFMAQ(0);
    __builtin_amdgcn_s_barrier();
    // ---- ph3: quadrant (rh1, k1) ----
    LOADA(1, 1, cur);
    __builtin_amdgcn_s_barrier();
    MFMAQ(1);
    if (kt + 2 < nk)      asm volatile("s_waitcnt vmcnt(8)" ::: "memory");
    else if (kt + 1 < nk) asm volatile("s_waitcnt vmcnt(4)" ::: "memory");
    __builtin_amdgcn_s_barrier();
  }
#undef STAGEU
#undef LOADA
#undef LOADB
#undef MFMAQ

  // ---- epilogue ----
  #pragma unroll
  for (int mm = 0; mm < 8; ++mm) {
    int row = m0 + wr * 128 + (mm >> 2) * 64 + (mm & 3) * 16 + lg * 4;
    #pragma unroll
    for (int n = 0; n < 4; ++n) {
      int col = n0 + wc * 64 + n * 16 + lr;
      if (col < N) {
        #pragma unroll
        for (int r = 0; r < 4; ++r) {
          if constexpr (OUT_BF16)
            ((u16*)Cptr)[(size_t)(row + r) * N + col] = f2b(acc[mm][n][r]);
          else
            ((float*)Cptr)[(size_t)(row + r) * N + col] = acc[mm][n][r];
        }
      }
    }
  }
}

// ---- RoPE + extract q/k/v from fused qkv (bf16 in) -------------------------
__global__ __launch_bounds__(256) void rope_extract(
    const u16* __restrict__ fused, const int* __restrict__ pos_ids,
    u16* __restrict__ q, u16* __restrict__ kx, u16* __restrict__ vT)
{
  const int t   = threadIdx.x;
  const int row = blockIdx.x * 4 + (t >> 6);
  const int d   = t & 63;
  const int b   = row >> 10, s = row & 1023;
  const float p = (float)pos_ids[s];
  const float inv = exp2f(-0.41524101186092029f * (float)(d & 31));
  float sn, cs;
  sincosf(p * inv, &sn, &cs);
  const float sgn = (d < 32) ? -1.f : 1.f;
  const int dp = (d + 32) & 63;
  const u16* base = fused + (size_t)row * 4672;

  for (int h = 0; h < 71; ++h) {
    float x  = b2f(base[h * 64 + d]);
    float xp = b2f(base[h * 64 + dp]);
    q[((size_t)(b * 71 + h) * 1024 + s) * 64 + d] = f2b(x * cs + sgn * xp * sn);
  }
  {
    float x  = b2f(base[71 * 64 + d]);
    float xp = b2f(base[71 * 64 + dp]);
    kx[((size_t)b * 1024 + s) * 64 + d] = f2b(x * cs + sgn * xp * sn);
  }
  vT[((size_t)b * 64 + d) * 1024 + s] = base[72 * 64 + d];
}

// ---- flash attention (causal, MQA): swapped-QK 32x32 MFMA, in-reg softmax --
__global__ __launch_bounds__(128) void attn_kernel(
    const u16* __restrict__ q, const u16* __restrict__ kx,
    const u16* __restrict__ vT, u16* __restrict__ attnO)
{
  const int t = threadIdx.x, lane = t & 63, w = t >> 6;
  const int lq  = lane & 31;
  const int hi  = lane >> 5;
  const int hi4 = hi << 2;
  const int pair = blockIdx.x, h = blockIdx.y, b = blockIdx.z;
  const int qt = w ? (31 - pair) : pair;
  const int q0 = qt * 32;

  const u16* qbase = q + ((size_t)(b * 71 + h) * 1024 + q0 + lq) * 64 + hi * 8;
  s16x8 qf[4];
  #pragma unroll
  for (int kt = 0; kt < 4; ++kt) qf[kt] = *(const s16x8*)(qbase + kt * 16);

  f32x16 o0 = {}, o1 = {};
  float m = -1e30f, l = 0.f;

  const u16* kbase  = kx + ((size_t)b * 1024 + lq) * 64 + hi * 8;
  const u16* vbase0 = vT + ((size_t)b * 64 + lq) * 1024 + hi * 8;
  const u16* vbase1 = vbase0 + 32 * 1024;

  for (int it = 0; it <= qt; ++it) {
    const int kv0 = it * 32;
    s16x8 kf[4];
    #pragma unroll
    for (int kt = 0; kt < 4; ++kt)
      kf[kt] = *(const s16x8*)(kbase + (size_t)kv0 * 64 + kt * 16);
    s16x8 v00 = *(const s16x8*)(vbase0 + kv0);
    s16x8 v01 = *(const s16x8*)(vbase0 + kv0 + 16);
    s16x8 v10 = *(const s16x8*)(vbase1 + kv0);
    s16x8 v11 = *(const s16x8*)(vbase1 + kv0 + 16);

    f32x16 sa = {}, sb = {};
    sa = __builtin_amdgcn_mfma_f32_32x32x16_bf16(kf[0], qf[0], sa, 0, 0, 0);
    sb = __builtin_amdgcn_mfma_f32_32x32x16_bf16(kf[1], qf[1], sb, 0, 0, 0);
    sa = __builtin_amdgcn_mfma_f32_32x32x16_bf16(kf[2], qf[2], sa, 0, 0, 0);
    sb = __builtin_amdgcn_mfma_f32_32x32x16_bf16(kf[3], qf[3], sb, 0, 0, 0);

    float s[16];
    float pmax = -1e30f;
    if (it == qt) {
      #pragma unroll
      for (int r = 0; r < 16; ++r) {
        int R = (r & 3) + ((r >> 2) << 3) + hi4;
        s[r] = (R > lq) ? -1e30f : (sa[r] + sb[r]) * 0.125f;
        pmax = fmaxf(pmax, s[r]);
      }
    } else {
      #pragma unroll
      for (int r = 0; r < 16; ++r) {
        s[r] = (sa[r] + sb[r]) * 0.125f;
        pmax = fmaxf(pmax, s[r]);
      }
    }
    pmax = fmaxf(pmax, __shfl_xor(pmax, 32));

    if (!__all(pmax <= m + 8.f)) {
      float mn = fmaxf(m, pmax);
      float corr = __expf(m - mn);
      m = mn;
      l *= corr;
      #pragma unroll
      for (int r = 0; r < 16; ++r) {
        float c2 = __shfl(corr, (r & 3) + ((r >> 2) << 3) + hi4);
        o0[r] *= c2; o1[r] *= c2;
      }
    }

    float p[16], sum = 0.f;
    #pragma unroll
    for (int r = 0; r < 16; ++r) { p[r] = __expf(s[r] - m); sum += p[r]; }
    sum += __shfl_xor(sum, 32);
    l += sum;

    unsigned int a0 = cvtpk(p[0], p[1]),   a1 = cvtpk(p[2], p[3]);
    unsigned int b0 = cvtpk(p[4], p[5]),   b1 = cvtpk(p[6], p[7]);
    asm("v_permlane32_swap_b32 %0, %1" : "+v"(a0), "+v"(b0));
    asm("v_permlane32_swap_b32 %0, %1" : "+v"(a1), "+v"(b1));
    unsigned int c0 = cvtpk(p[8], p[9]),   c1 = cvtpk(p[10], p[11]);
    unsigned int d0 = cvtpk(p[12], p[13]), d1 = cvtpk(p[14], p[15]);
    asm("v_permlane32_swap_b32 %0, %1" : "+v"(c0), "+v"(d0));
    asm("v_permlane32_swap_b32 %0, %1" : "+v"(c1), "+v"(d1));
    union { unsigned int wd[4]; s16x8 v; } palo, pahi;
    palo.wd[0] = a0; palo.wd[1] = a1; palo.wd[2] = b0; palo.wd[3] = b1;
    pahi.wd[0] = c0; pahi.wd[1] = c1; pahi.wd[2] = d0; pahi.wd[3] = d1;

    o0 = __builtin_amdgcn_mfma_f32_32x32x16_bf16(palo.v, v00, o0, 0, 0, 0);
    o0 = __builtin_amdgcn_mfma_f32_32x32x16_bf16(pahi.v, v01, o0, 0, 0, 0);
    o1 = __builtin_amdgcn_mfma_f32_32x32x16_bf16(palo.v, v10, o1, 0, 0, 0);
    o1 = __builtin_amdgcn_mfma_f32_32x32x16_bf16(pahi.v, v11, o1, 0, 0, 0);
  }

  float linv = 1.f / l;
  #pragma unroll
  for (int r = 0; r < 16; ++r) {
    int R = (r & 3) + ((r >> 2) << 3) + hi4;
    float c2 = __shfl(linv, R);
    size_t base = ((size_t)(b * 1024 + q0 + R) * 71 + h) * 64;
    attnO[base + lq]      = f2b(o0[r] * c2);
    attnO[base + 32 + lq] = f2b(o1[r] * c2);
  }
}

// ---- launcher --------------------------------------------------------------
extern "C" void kernel_launch(void* const* d_in, const int* in_sizes, int n_in,
                              void* d_out, int out_size, void* d_ws, size_t ws_size,
                              hipStream_t stream) {
  const float* hidden = (const float*)d_in[0];   // [2,1024,4544]
  const float* Wqkv   = (const float*)d_in[1];   // [4544,4672]
  const float* Wdense = (const float*)d_in[2];   // [4544,4544]
  const int*   pos    = (const int*)d_in[4];     // [1,1024]
  float* out = (float*)d_out;                    // [2,1024,4544] fp32

  char* wsp = (char*)d_ws;
  // buffer plan:
  //  Wt:    4864 x 4544 bf16 = 44,208,128  (shared by both GEMMs; zero-padded)
  //  A1:    18,612,224  (hidden bf16 -> later q)
  //  fused: 19,136,512  (bf16 -> later attn output)
  //  k,vT:  262,144 each
  u16* Wt    = (u16*)(wsp);
  u16* A1    = (u16*)(wsp + 44208128);
  u16* fused = (u16*)(wsp + 44208128 + 18612224);
  u16* kws   = (u16*)(wsp + 44208128 + 18612224 + 19136512);
  u16* vws   = (u16*)(wsp + 44208128 + 18612224 + 19136512 + 262144);
  u16* qws   = A1;
  u16* attnw = fused;

  // 1) hidden -> bf16
  conv_bf16<<<4544, 256, 0, stream>>>(hidden, A1, 2048 * 4544 / 8);
  // 2) W_qkv^T -> bf16 [4864][4544] (zero-padded to 19*256 rows)
  transpose_conv<<<dim3(76, 71), 256, 0, stream>>>(Wqkv, Wt, 4544, 4672);
  // 3) fused = A1 @ Wqkv  (M=2048, Npad=4864, K=4544): 8*19 = 152 blocks
  gemm256<true><<<152, 512, 0, stream>>>(A1, Wt, fused, 2048, 4672, 4544, 19);
  // 4) RoPE + split
  rope_extract<<<512, 256, 0, stream>>>(fused, pos, qws, kws, vws);
  // 5) W_dense^T -> bf16 [4608][4544]
  transpose_conv<<<dim3(72, 71), 256, 0, stream>>>(Wdense, Wt, 4544, 4544);
  // 6) attention
  attn_kernel<<<dim3(16, 71, 2), 128, 0, stream>>>(qws, kws, vws, attnw);
  // 7) out = attn @ W_dense (M=2048, Npad=4608, K=4544): 8*18 = 144 blocks
  gemm256<false><<<144, 512, 0, stream>>>(attnw, Wt, out, 2048, 4544, 4544, 18);
}

// Round 5
// 448.675 us; speedup vs baseline: 1.2601x; 1.2601x over previous
//
#include <hip/hip_runtime.h>

typedef unsigned short u16;
using f32x4  = __attribute__((ext_vector_type(4))) float;
using f32x16 = __attribute__((ext_vector_type(16))) float;
using s16x8  = __attribute__((ext_vector_type(8))) short;

// ---- helpers ---------------------------------------------------------------
static __device__ __forceinline__ u16 f2b(float f) {
  unsigned int u = __builtin_bit_cast(unsigned int, f);
  u = (u + 0x7fffu + ((u >> 16) & 1u)) >> 16;   // RNE, finite inputs only
  return (u16)u;
}
static __device__ __forceinline__ float b2f(u16 h) {
  unsigned int u = ((unsigned int)h) << 16;
  return __builtin_bit_cast(float, u);
}
static __device__ __forceinline__ unsigned int cvtpk(float lo, float hi) {
  unsigned int r;
  asm("v_cvt_pk_bf16_f32 %0, %1, %2" : "=v"(r) : "v"(lo), "v"(hi));
  return r;
}
static __device__ __forceinline__ void gload16(const void* g, void* l) {
  __builtin_amdgcn_global_load_lds(
      (const __attribute__((address_space(1))) void*)g,
      (__attribute__((address_space(3))) void*)l, 16, 0, 0);
}

// ---- fp32 -> bf16 elementwise (8/thread) -----------------------------------
__global__ __launch_bounds__(256) void conv_bf16(
    const float* __restrict__ in, u16* __restrict__ out, int n8)
{
  int i = blockIdx.x * 256 + threadIdx.x;
  if (i >= n8) return;
  float4 a = *(const float4*)(in + (size_t)i * 8);
  float4 b = *(const float4*)(in + (size_t)i * 8 + 4);
  __align__(16) u16 tmp[8] = {f2b(a.x), f2b(a.y), f2b(a.z), f2b(a.w),
                              f2b(b.x), f2b(b.y), f2b(b.z), f2b(b.w)};
  *(uint4*)(out + (size_t)i * 8) = *(const uint4*)tmp;
}

// ---- W[K][N] fp32 -> Wt[Npad][K] bf16 (transpose+convert, zero pad) --------
__global__ __launch_bounds__(256) void transpose_conv(
    const float* __restrict__ W, u16* __restrict__ Wt, int K, int N)
{
  __shared__ u16 tile[64][72];
  const int t = threadIdx.x;
  const int n0 = blockIdx.x * 64, k0 = blockIdx.y * 64;
  #pragma unroll
  for (int i = 0; i < 4; ++i) {
    int idx = i * 256 + t;
    int r = idx >> 4;
    int c = (idx & 15) << 2;
    float4 v = make_float4(0.f, 0.f, 0.f, 0.f);
    if (n0 + c < N) v = *(const float4*)(W + (size_t)(k0 + r) * N + n0 + c);
    tile[r][c + 0] = f2b(v.x);
    tile[r][c + 1] = f2b(v.y);
    tile[r][c + 2] = f2b(v.z);
    tile[r][c + 3] = f2b(v.w);
  }
  __syncthreads();
  #pragma unroll
  for (int i = 0; i < 2; ++i) {
    int idx = i * 256 + t;
    int rn = idx >> 3;
    int c8 = (idx & 7) << 3;
    __align__(16) u16 tmp[8];
    #pragma unroll
    for (int j = 0; j < 8; ++j) tmp[j] = tile[c8 + j][rn];
    *(uint4*)(Wt + (size_t)(n0 + rn) * K + k0 + c8) = *(const uint4*)tmp;
  }
}

// ---- GEMM: C[M,N] = A[M,K] * B^T  (A bf16 [M][K], B bf16 [Npad][K]) --------
// m97 structure: 128x128 tile, 4 waves (2x2 of 64x64), BK=32, global_load_lds.
// 1-D grid (gridDim.x % 8 == 0), XCD-chunked swizzle.
// MODE 0: plain fp32 C store.  MODE 2: fused RoPE epilogue for the QKV GEMM —
// each wave's 64-col span is one head h; rotate_half pairs are acc[m][n] vs
// acc[m][n^2] in registers. h<71 -> q (roped), h==71 -> k (roped), h==72 -> vT.
template<int MODE>
__global__ __launch_bounds__(256) void gemm_bt(
    const u16* __restrict__ A, const u16* __restrict__ B,
    float* __restrict__ Cptr,
    u16* __restrict__ qo, u16* __restrict__ ko, u16* __restrict__ vo,
    const int* __restrict__ pos,
    int M, int N, int K, int NBX)
{
  __shared__ __align__(16) u16 aLds[128 * 32];
  __shared__ __align__(16) u16 bLds[128 * 32];

  const int t = threadIdx.x, lane = t & 63, w = t >> 6;
  const int lr = lane & 15, lg = lane >> 4;
  const int wr = w >> 1, wc = w & 1;

  const int bid = blockIdx.x;
  const int qq  = gridDim.x >> 3;
  const int swz = (bid & 7) * qq + (bid >> 3);    // bijective: grid % 8 == 0
  const int m0 = (swz / NBX) * 128, n0 = (swz % NBX) * 128;

  const int srow = lane >> 2;
  const int skc  = (lane & 3) << 3;

  f32x4 acc[4][4] = {};

  const int nk = K >> 5;
  for (int kt = 0; kt < nk; ++kt) {
    const int k0 = kt << 5;
    __syncthreads();
    #pragma unroll
    for (int i = 0; i < 2; ++i) {
      int row = i * 64 + w * 16 + srow;
      gload16(A + (size_t)(m0 + row) * K + k0 + skc,
              (char*)aLds + i * 4096 + w * 1024);
      gload16(B + (size_t)(n0 + row) * K + k0 + skc,
              (char*)bLds + i * 4096 + w * 1024);
    }
    __syncthreads();
    s16x8 af[4], bf[4];
    #pragma unroll
    for (int m = 0; m < 4; ++m)
      af[m] = *(const s16x8*)(aLds + (wr * 64 + m * 16 + lr) * 32 + lg * 8);
    #pragma unroll
    for (int n = 0; n < 4; ++n)
      bf[n] = *(const s16x8*)(bLds + (wc * 64 + n * 16 + lr) * 32 + lg * 8);
    #pragma unroll
    for (int m = 0; m < 4; ++m)
      #pragma unroll
      for (int n = 0; n < 4; ++n)
        acc[m][n] = __builtin_amdgcn_mfma_f32_16x16x32_bf16(af[m], bf[n], acc[m][n], 0, 0, 0);
  }

  if constexpr (MODE == 0) {
    #pragma unroll
    for (int m = 0; m < 4; ++m) {
      int row = m0 + wr * 64 + m * 16 + lg * 4;
      #pragma unroll
      for (int n = 0; n < 4; ++n) {
        int col = n0 + wc * 64 + n * 16 + lr;
        if (col < N) {
          #pragma unroll
          for (int r = 0; r < 4; ++r)
            Cptr[(size_t)(row + r) * N + col] = acc[m][n][r];
        }
      }
    }
  } else {
    const int h = (n0 + wc * 64) >> 6;       // head index for this wave
    if (h > 72) return;                       // zero-padded columns
    const float inv0 = exp2f(-0.41524101186092029f * (float)lr);
    const float inv1 = exp2f(-0.41524101186092029f * (float)(16 + lr));
    #pragma unroll
    for (int m = 0; m < 4; ++m) {
      #pragma unroll
      for (int r = 0; r < 4; ++r) {
        int row = m0 + wr * 64 + m * 16 + lg * 4 + r;
        int b = row >> 10, s = row & 1023;
        if (h == 72) {                        // V: no rope, transposed store
          #pragma unroll
          for (int n = 0; n < 4; ++n) {
            int d = n * 16 + lr;
            vo[((size_t)b * 64 + d) * 1024 + s] = f2b(acc[m][n][r]);
          }
        } else {                              // Q / K: rope in registers
          float p = (float)pos[s];
          float sn0, cs0, sn1, cs1;
          __sincosf(p * inv0, &sn0, &cs0);
          __sincosf(p * inv1, &sn1, &cs1);
          #pragma unroll
          for (int n = 0; n < 4; ++n) {
            float cs  = (n & 1) ? cs1 : cs0;
            float sn  = (n & 1) ? sn1 : sn0;
            float sgn = (n < 2) ? -1.f : 1.f;
            float val = acc[m][n][r] * cs + sgn * acc[m][n ^ 2][r] * sn;
            int d = n * 16 + lr;
            if (h < 71)
              qo[((size_t)(b * 71 + h) * 1024 + s) * 64 + d] = f2b(val);
            else
              ko[((size_t)b * 1024 + s) * 64 + d] = f2b(val);
          }
        }
      }
    }
  }
}

// ---- flash attention (causal, MQA): swapped-QK 32x32 MFMA, in-reg softmax --
__global__ __launch_bounds__(128) void attn_kernel(
    const u16* __restrict__ q, const u16* __restrict__ kx,
    const u16* __restrict__ vT, u16* __restrict__ attnO)
{
  const int t = threadIdx.x, lane = t & 63, w = t >> 6;
  const int lq  = lane & 31;
  const int hi  = lane >> 5;
  const int hi4 = hi << 2;
  const int pair = blockIdx.x, h = blockIdx.y, b = blockIdx.z;
  const int qt = w ? (31 - pair) : pair;
  const int q0 = qt * 32;

  const u16* qbase = q + ((size_t)(b * 71 + h) * 1024 + q0 + lq) * 64 + hi * 8;
  s16x8 qf[4];
  #pragma unroll
  for (int kt = 0; kt < 4; ++kt) qf[kt] = *(const s16x8*)(qbase + kt * 16);

  f32x16 o0 = {}, o1 = {};
  float m = -1e30f, l = 0.f;

  const u16* kbase  = kx + ((size_t)b * 1024 + lq) * 64 + hi * 8;
  const u16* vbase0 = vT + ((size_t)b * 64 + lq) * 1024 + hi * 8;
  const u16* vbase1 = vbase0 + 32 * 1024;

  for (int it = 0; it <= qt; ++it) {
    const int kv0 = it * 32;
    s16x8 kf[4];
    #pragma unroll
    for (int kt = 0; kt < 4; ++kt)
      kf[kt] = *(const s16x8*)(kbase + (size_t)kv0 * 64 + kt * 16);
    s16x8 v00 = *(const s16x8*)(vbase0 + kv0);
    s16x8 v01 = *(const s16x8*)(vbase0 + kv0 + 16);
    s16x8 v10 = *(const s16x8*)(vbase1 + kv0);
    s16x8 v11 = *(const s16x8*)(vbase1 + kv0 + 16);

    f32x16 sa = {}, sb = {};
    sa = __builtin_amdgcn_mfma_f32_32x32x16_bf16(kf[0], qf[0], sa, 0, 0, 0);
    sb = __builtin_amdgcn_mfma_f32_32x32x16_bf16(kf[1], qf[1], sb, 0, 0, 0);
    sa = __builtin_amdgcn_mfma_f32_32x32x16_bf16(kf[2], qf[2], sa, 0, 0, 0);
    sb = __builtin_amdgcn_mfma_f32_32x32x16_bf16(kf[3], qf[3], sb, 0, 0, 0);

    float s[16];
    float pmax = -1e30f;
    if (it == qt) {
      #pragma unroll
      for (int r = 0; r < 16; ++r) {
        int R = (r & 3) + ((r >> 2) << 3) + hi4;
        s[r] = (R > lq) ? -1e30f : (sa[r] + sb[r]) * 0.125f;
        pmax = fmaxf(pmax, s[r]);
      }
    } else {
      #pragma unroll
      for (int r = 0; r < 16; ++r) {
        s[r] = (sa[r] + sb[r]) * 0.125f;
        pmax = fmaxf(pmax, s[r]);
      }
    }
    pmax = fmaxf(pmax, __shfl_xor(pmax, 32));

    if (!__all(pmax <= m + 8.f)) {
      float mn = fmaxf(m, pmax);
      float corr = __expf(m - mn);
      m = mn;
      l *= corr;
      #pragma unroll
      for (int r = 0; r < 16; ++r) {
        float c2 = __shfl(corr, (r & 3) + ((r >> 2) << 3) + hi4);
        o0[r] *= c2; o1[r] *= c2;
      }
    }

    float p[16], sum = 0.f;
    #pragma unroll
    for (int r = 0; r < 16; ++r) { p[r] = __expf(s[r] - m); sum += p[r]; }
    sum += __shfl_xor(sum, 32);
    l += sum;

    unsigned int a0 = cvtpk(p[0], p[1]),   a1 = cvtpk(p[2], p[3]);
    unsigned int b0 = cvtpk(p[4], p[5]),   b1 = cvtpk(p[6], p[7]);
    asm("v_permlane32_swap_b32 %0, %1" : "+v"(a0), "+v"(b0));
    asm("v_permlane32_swap_b32 %0, %1" : "+v"(a1), "+v"(b1));
    unsigned int c0 = cvtpk(p[8], p[9]),   c1 = cvtpk(p[10], p[11]);
    unsigned int d0 = cvtpk(p[12], p[13]), d1 = cvtpk(p[14], p[15]);
    asm("v_permlane32_swap_b32 %0, %1" : "+v"(c0), "+v"(d0));
    asm("v_permlane32_swap_b32 %0, %1" : "+v"(c1), "+v"(d1));
    union { unsigned int wd[4]; s16x8 v; } palo, pahi;
    palo.wd[0] = a0; palo.wd[1] = a1; palo.wd[2] = b0; palo.wd[3] = b1;
    pahi.wd[0] = c0; pahi.wd[1] = c1; pahi.wd[2] = d0; pahi.wd[3] = d1;

    o0 = __builtin_amdgcn_mfma_f32_32x32x16_bf16(palo.v, v00, o0, 0, 0, 0);
    o0 = __builtin_amdgcn_mfma_f32_32x32x16_bf16(pahi.v, v01, o0, 0, 0, 0);
    o1 = __builtin_amdgcn_mfma_f32_32x32x16_bf16(palo.v, v10, o1, 0, 0, 0);
    o1 = __builtin_amdgcn_mfma_f32_32x32x16_bf16(pahi.v, v11, o1, 0, 0, 0);
  }

  float linv = 1.f / l;
  #pragma unroll
  for (int r = 0; r < 16; ++r) {
    int R = (r & 3) + ((r >> 2) << 3) + hi4;
    float c2 = __shfl(linv, R);
    size_t base = ((size_t)(b * 1024 + q0 + R) * 71 + h) * 64;
    attnO[base + lq]      = f2b(o0[r] * c2);
    attnO[base + 32 + lq] = f2b(o1[r] * c2);
  }
}

// ---- launcher --------------------------------------------------------------
extern "C" void kernel_launch(void* const* d_in, const int* in_sizes, int n_in,
                              void* d_out, int out_size, void* d_ws, size_t ws_size,
                              hipStream_t stream) {
  const float* hidden = (const float*)d_in[0];   // [2,1024,4544]
  const float* Wqkv   = (const float*)d_in[1];   // [4544,4672]
  const float* Wdense = (const float*)d_in[2];   // [4544,4544]
  const int*   pos    = (const int*)d_in[4];     // [1,1024]
  float* out = (float*)d_out;                    // [2,1024,4544] fp32

  char* wsp = (char*)d_ws;
  // buffer plan (82.0 MB total):
  //  Wt:   4736 x 4544 bf16 = 43,040,768   (shared by both GEMMs; zero-padded)
  //  A1:   18,612,224  hidden bf16 -> (after GEMM1) reused as attn output
  //  q:    18,612,224
  //  k,vT: 262,144 each
  u16* Wt    = (u16*)(wsp);
  u16* A1    = (u16*)(wsp + 43040768);
  u16* qws   = (u16*)(wsp + 43040768 + 18612224);
  u16* kws   = (u16*)(wsp + 43040768 + 18612224 + 18612224);
  u16* vws   = (u16*)(wsp + 43040768 + 18612224 + 18612224 + 262144);
  u16* attnw = A1;     // A1 dead after GEMM1 reads it

  // 1) hidden -> bf16
  conv_bf16<<<4544, 256, 0, stream>>>(hidden, A1, 2048 * 4544 / 8);
  // 2) W_qkv^T -> bf16 [4736][4544] (zero-padded)
  transpose_conv<<<dim3(74, 71), 256, 0, stream>>>(Wqkv, Wt, 4544, 4672);
  // 3) QKV GEMM with fused RoPE/split epilogue (M=2048, Npad=4736, K=4544)
  gemm_bt<2><<<592, 256, 0, stream>>>(A1, Wt, nullptr, qws, kws, vws, pos,
                                      2048, 4672, 4544, 37);
  // 4) W_dense^T -> bf16 [4608][4544]
  transpose_conv<<<dim3(72, 71), 256, 0, stream>>>(Wdense, Wt, 4544, 4544);
  // 5) attention (writes attnw = A1)
  attn_kernel<<<dim3(16, 71, 2), 128, 0, stream>>>(qws, kws, vws, attnw);
  // 6) out = attn @ W_dense (M=2048, Npad=4608, K=4544), fp32 out
  gemm_bt<0><<<576, 256, 0, stream>>>(attnw, Wt, out, nullptr, nullptr, nullptr,
                                      nullptr, 2048, 4544, 4544, 36);
}